// Round 6
// baseline (560.591 us; speedup 1.0000x reference)
//
#include <hip/hip_runtime.h>
#include <hip/hip_bf16.h>
#include <cstdint>

// Problem constants (b=2, s=4096, dim=1024, heads=64, dim_head=64)
#define M_TOK 8192
#define DIM   1024
#define INNER 4096
#define HEADS 64
#define DH    64
#define QSCALE 0.125f      // 64^-0.5
#define EPS    1e-6f

typedef __hip_bfloat16 bf16;
typedef __bf16 bf16x8_t __attribute__((ext_vector_type(8)));
typedef float f32x4_t __attribute__((ext_vector_type(4)));

__device__ __forceinline__ float bfbits2f(unsigned short u) {
  return __uint_as_float(((unsigned)u) << 16);
}
__device__ __forceinline__ unsigned short f2bfbits(float f) {
  __hip_bfloat16 h = __float2bfloat16(f);
  unsigned short u;
  __builtin_memcpy(&u, &h, 2);
  return u;
}

// async global->LDS, 16B per lane. LDS dst must be wave-uniform base + lane*16.
__device__ __forceinline__ void load_lds16(const void* g, void* l) {
  __builtin_amdgcn_global_load_lds(
      (__attribute__((address_space(1))) void*)g,
      (__attribute__((address_space(3))) void*)l, 16, 0, 0);
}

// XCD-aware block swizzle: XCD x owns M-tiles [x*gy/8, (x+1)*gy/8), N-major
// within the XCD. (R3: cut gemm_out FETCH_SIZE 270->66 MB.)
__device__ __forceinline__ void swizzle_xy(int& bx, int& by) {
  const int gx = gridDim.x, gy = gridDim.y;
  const int id  = blockIdx.x + gx * blockIdx.y;
  const int per = gy >> 3;          // M-tiles per XCD (gy % 8 == 0)
  const int xcd = id & 7;
  const int s   = id >> 3;
  by = xcd * per + (s % per);
  bx = s / per;
}

// ---------------------------------------------------------------------------
// prep: z=0 -> cast x fp32->bf16 (2 float4/thread) + zero ks;
//       z=1 -> Wk^T into Wt[0:..); z=2 -> Wv^T into Wt[R*C:..).
// grid (128, 32, 3) x 256 threads.
// ---------------------------------------------------------------------------
__global__ __launch_bounds__(256) void prep_kernel(
    const float* __restrict__ x, const float* __restrict__ Wk,
    const float* __restrict__ Wv, unsigned short* __restrict__ xb,
    unsigned short* __restrict__ Wt, float* __restrict__ ks)
{
  if (blockIdx.z == 0) {
    const int id = blockIdx.y * 128 + blockIdx.x;      // 0..4095
    const int t0 = id * 256 + threadIdx.x;             // 0..1048575
#pragma unroll
    for (int j = 0; j < 2; ++j) {
      const int i = t0 * 2 + j;                        // float4 index
      const float4 v = reinterpret_cast<const float4*>(x)[i];
      ushort4 o;
      o.x = f2bfbits(v.x); o.y = f2bfbits(v.y);
      o.z = f2bfbits(v.z); o.w = f2bfbits(v.w);
      reinterpret_cast<ushort4*>(xb)[i] = o;
    }
    if (t0 < M_TOK * DH) ks[t0] = 0.f;                 // zero ksum accumulator
  } else {
    __shared__ float tile[32][33];
    const float* W = (blockIdx.z == 1) ? Wk : Wv;
    unsigned short* dst = Wt + (size_t)(blockIdx.z - 1) * DIM * INNER;
    const int bx = blockIdx.x * 32;   // C offset (INNER)
    const int by = blockIdx.y * 32;   // R offset (DIM)
    const int tx = threadIdx.x & 31;
    const int ty = threadIdx.x >> 5;  // 0..7
#pragma unroll
    for (int k = 0; k < 4; ++k)
      tile[ty + k * 8][tx] = W[(size_t)(by + ty + k * 8) * INNER + bx + tx];
    __syncthreads();
#pragma unroll
    for (int k = 0; k < 4; ++k)
      dst[(size_t)(bx + ty + k * 8) * DIM + by + tx] = f2bfbits(tile[tx][ty + k * 8]);
  }
}

// ---------------------------------------------------------------------------
// transpose-cast: W [R][C] fp32 -> Wt [C][R] bf16.  32x32 LDS tiles.
// ---------------------------------------------------------------------------
__global__ __launch_bounds__(256) void tcast_kernel(
    const float* __restrict__ W, unsigned short* __restrict__ Wt, int R, int C)
{
  __shared__ float tile[32][33];
  const int bx = blockIdx.x * 32;   // C offset
  const int by = blockIdx.y * 32;   // R offset
  const int tx = threadIdx.x & 31;
  const int ty = threadIdx.x >> 5;  // 0..7
#pragma unroll
  for (int k = 0; k < 4; ++k)
    tile[ty + k * 8][tx] = W[(size_t)(by + ty + k * 8) * C + bx + tx];
  __syncthreads();
#pragma unroll
  for (int k = 0; k < 4; ++k)
    Wt[(size_t)(bx + ty + k * 8) * R + by + tx] = f2bfbits(tile[tx][ty + k * 8]);
}

// ---------------------------------------------------------------------------
// MFMA GEMM, 128x128 tile, BK=64 (R5-validated: 864 TF, MfmaUtil 40%).
// MODE: 0 = identity, 1 = relu, 2 = relu*QSCALE
// ---------------------------------------------------------------------------
template <int MODE>
__global__ __launch_bounds__(256) void gemm_bf16(
    const unsigned short* __restrict__ A,   // [M][K] bf16
    const unsigned short* __restrict__ Bt,  // [N][K] bf16 (B transposed)
    unsigned short* __restrict__ C,         // [M][N] bf16
    int M, int N, int K)
{
  __shared__ __align__(16) unsigned short As[128 * 64];  // 16 KB
  __shared__ __align__(16) unsigned short Bs[128 * 64];  // 16 KB

  int bxi, byi;
  swizzle_xy(bxi, byi);
  const int tid  = threadIdx.x;
  const int bm   = byi * 128;
  const int bn   = bxi * 128;
  const int lane = tid & 63;
  const int w    = tid >> 6;
  const int wm   = (w & 1) * 64;
  const int wn   = (w >> 1) * 64;
  const int quad = lane >> 4;
  const int l15  = lane & 15;

  f32x4_t acc[4][4];
#pragma unroll
  for (int mt = 0; mt < 4; ++mt)
#pragma unroll
    for (int nt = 0; nt < 4; ++nt) acc[mt][nt] = (f32x4_t){0.f, 0.f, 0.f, 0.f};

  int qa[4], ra[4], ca[4];
#pragma unroll
  for (int j = 0; j < 4; ++j) {
    qa[j] = tid + 256 * j;
    ra[j] = qa[j] >> 3;
    ca[j] = (qa[j] & 7) ^ (ra[j] & 7);
  }

  for (int k0 = 0; k0 < K; k0 += 64) {
    __syncthreads();
#pragma unroll
    for (int j = 0; j < 4; ++j) {
      load_lds16(&A [(size_t)(bm + ra[j]) * K + k0 + ca[j] * 8], &As[qa[j] * 8]);
      load_lds16(&Bt[(size_t)(bn + ra[j]) * K + k0 + ca[j] * 8], &Bs[qa[j] * 8]);
    }
    __syncthreads();

    bf16x8_t af[4][2], bfr[4][2];
#pragma unroll
    for (int mt = 0; mt < 4; ++mt) {
      const int r = wm + mt * 16 + l15;
#pragma unroll
      for (int kt = 0; kt < 2; ++kt) {
        const int slot = (kt * 4 + quad) ^ (r & 7);
        af[mt][kt] = *reinterpret_cast<const bf16x8_t*>(&As[r * 64 + slot * 8]);
      }
    }
#pragma unroll
    for (int nt = 0; nt < 4; ++nt) {
      const int r = wn + nt * 16 + l15;
#pragma unroll
      for (int kt = 0; kt < 2; ++kt) {
        const int slot = (kt * 4 + quad) ^ (r & 7);
        bfr[nt][kt] = *reinterpret_cast<const bf16x8_t*>(&Bs[r * 64 + slot * 8]);
      }
    }
#pragma unroll
    for (int mt = 0; mt < 4; ++mt)
#pragma unroll
      for (int nt = 0; nt < 4; ++nt) {
        acc[mt][nt] = __builtin_amdgcn_mfma_f32_16x16x32_bf16(
            af[mt][0], bfr[nt][0], acc[mt][nt], 0, 0, 0);
        acc[mt][nt] = __builtin_amdgcn_mfma_f32_16x16x32_bf16(
            af[mt][1], bfr[nt][1], acc[mt][nt], 0, 0, 0);
      }
  }

#pragma unroll
  for (int mt = 0; mt < 4; ++mt)
#pragma unroll
    for (int i = 0; i < 4; ++i) {
      const size_t rowg = (size_t)(bm + wm + mt * 16 + quad * 4 + i);
#pragma unroll
      for (int nt = 0; nt < 4; ++nt) {
        float v = acc[mt][nt][i];
        if (MODE >= 1) v = fmaxf(v, 0.f);
        if (MODE == 2) v *= QSCALE;
        C[rowg * N + bn + wn + nt * 16 + l15] = f2bfbits(v);
      }
    }
}

// ---------------------------------------------------------------------------
// Fused K+V projection, BK=64. Bt = [Wk^T ; Wv^T] [8192][1024].
// bn >= 4096 -> V tile, stored.  bn < 4096 -> K tile: NOT stored; epilogue
// does ks[t][d] += relu(k) via device-scope atomicAdd (d = nt*16+l15,
// identical for both wave columns since wn is 0/64).  K never touches HBM.
// ---------------------------------------------------------------------------
__global__ __launch_bounds__(256) void gemm_kv(
    const unsigned short* __restrict__ A,    // Xb [8192][1024]
    const unsigned short* __restrict__ Bt,   // [8192][1024]
    unsigned short* __restrict__ Vb,         // [8192][4096]
    float* __restrict__ ks,                  // [8192][64], pre-zeroed
    int K)
{
  __shared__ __align__(16) unsigned short As[128 * 64];
  __shared__ __align__(16) unsigned short Bs[128 * 64];

  int bxi, byi;
  swizzle_xy(bxi, byi);
  const int tid  = threadIdx.x;
  const int bm   = byi * 128;
  const int bn   = bxi * 128;
  const bool isK = (bn < 4096);
  const int bnc  = bn & 4095;
  const int lane = tid & 63;
  const int w    = tid >> 6;
  const int wm   = (w & 1) * 64;
  const int wn   = (w >> 1) * 64;
  const int quad = lane >> 4;
  const int l15  = lane & 15;

  f32x4_t acc[4][4];
#pragma unroll
  for (int mt = 0; mt < 4; ++mt)
#pragma unroll
    for (int nt = 0; nt < 4; ++nt) acc[mt][nt] = (f32x4_t){0.f, 0.f, 0.f, 0.f};

  int qa[4], ra[4], ca[4];
#pragma unroll
  for (int j = 0; j < 4; ++j) {
    qa[j] = tid + 256 * j;
    ra[j] = qa[j] >> 3;
    ca[j] = (qa[j] & 7) ^ (ra[j] & 7);
  }

  for (int k0 = 0; k0 < K; k0 += 64) {
    __syncthreads();
#pragma unroll
    for (int j = 0; j < 4; ++j) {
      load_lds16(&A [(size_t)(bm + ra[j]) * K + k0 + ca[j] * 8], &As[qa[j] * 8]);
      load_lds16(&Bt[(size_t)(bn + ra[j]) * K + k0 + ca[j] * 8], &Bs[qa[j] * 8]);
    }
    __syncthreads();

    bf16x8_t af[4][2], bfr[4][2];
#pragma unroll
    for (int mt = 0; mt < 4; ++mt) {
      const int r = wm + mt * 16 + l15;
#pragma unroll
      for (int kt = 0; kt < 2; ++kt) {
        const int slot = (kt * 4 + quad) ^ (r & 7);
        af[mt][kt] = *reinterpret_cast<const bf16x8_t*>(&As[r * 64 + slot * 8]);
      }
    }
#pragma unroll
    for (int nt = 0; nt < 4; ++nt) {
      const int r = wn + nt * 16 + l15;
#pragma unroll
      for (int kt = 0; kt < 2; ++kt) {
        const int slot = (kt * 4 + quad) ^ (r & 7);
        bfr[nt][kt] = *reinterpret_cast<const bf16x8_t*>(&Bs[r * 64 + slot * 8]);
      }
    }
#pragma unroll
    for (int mt = 0; mt < 4; ++mt)
#pragma unroll
      for (int nt = 0; nt < 4; ++nt) {
        acc[mt][nt] = __builtin_amdgcn_mfma_f32_16x16x32_bf16(
            af[mt][0], bfr[nt][0], acc[mt][nt], 0, 0, 0);
        acc[mt][nt] = __builtin_amdgcn_mfma_f32_16x16x32_bf16(
            af[mt][1], bfr[nt][1], acc[mt][nt], 0, 0, 0);
      }
  }

  if (isK) {
    // ks[t][d] += relu(k);  d = nt*16 + l15 (same for wn=0 and wn=64)
#pragma unroll
    for (int mt = 0; mt < 4; ++mt)
#pragma unroll
      for (int i = 0; i < 4; ++i) {
        const int rowg = bm + wm + mt * 16 + quad * 4 + i;
#pragma unroll
        for (int nt = 0; nt < 4; ++nt) {
          const float v = fmaxf(acc[mt][nt][i], 0.f);
          atomicAdd(&ks[rowg * DH + nt * 16 + l15], v);
        }
      }
  } else {
#pragma unroll
    for (int mt = 0; mt < 4; ++mt)
#pragma unroll
      for (int i = 0; i < 4; ++i) {
        const size_t rowg = (size_t)(bm + wm + mt * 16 + quad * 4 + i);
#pragma unroll
        for (int nt = 0; nt < 4; ++nt)
          Vb[rowg * 4096 + bnc + wn + nt * 16 + l15] = f2bfbits(acc[mt][nt][i]);
      }
  }
}

// ---------------------------------------------------------------------------
// Output MFMA GEMM: out[M,N] = A[M,K] @ Bt[N,K]^T + bias[N], fp32 out.
// 128(M) x 64(N) tile, BK=64 (R4-validated).
// ---------------------------------------------------------------------------
__global__ __launch_bounds__(256) void gemm_out_bf16(
    const unsigned short* __restrict__ A,   // [M][K] bf16
    const unsigned short* __restrict__ Bt,  // [N][K] bf16
    const float* __restrict__ bias,
    float* __restrict__ out, int M, int N, int K)
{
  __shared__ __align__(16) unsigned short As[128 * 64];  // 16 KB
  __shared__ __align__(16) unsigned short Bs[64 * 64];   //  8 KB

  int bxi, byi;
  swizzle_xy(bxi, byi);
  const int tid  = threadIdx.x;
  const int bm   = byi * 128;
  const int bn   = bxi * 64;
  const int lane = tid & 63;
  const int w    = tid >> 6;
  const int wm   = (w & 1) * 64;
  const int wn   = (w >> 1) * 32;
  const int quad = lane >> 4;
  const int l15  = lane & 15;

  f32x4_t acc[4][2];
#pragma unroll
  for (int mt = 0; mt < 4; ++mt)
#pragma unroll
    for (int nt = 0; nt < 2; ++nt) acc[mt][nt] = (f32x4_t){0.f, 0.f, 0.f, 0.f};

  int qa[4], ra[4], ca[4];
#pragma unroll
  for (int j = 0; j < 4; ++j) {
    qa[j] = tid + 256 * j;
    ra[j] = qa[j] >> 3;
    ca[j] = (qa[j] & 7) ^ (ra[j] & 7);
  }
  int qb[2], rb[2], cb[2];
#pragma unroll
  for (int j = 0; j < 2; ++j) {
    qb[j] = tid + 256 * j;
    rb[j] = qb[j] >> 3;
    cb[j] = (qb[j] & 7) ^ (rb[j] & 7);
  }

  for (int k0 = 0; k0 < K; k0 += 64) {
    __syncthreads();
#pragma unroll
    for (int j = 0; j < 4; ++j)
      load_lds16(&A[(size_t)(bm + ra[j]) * K + k0 + ca[j] * 8], &As[qa[j] * 8]);
#pragma unroll
    for (int j = 0; j < 2; ++j)
      load_lds16(&Bt[(size_t)(bn + rb[j]) * K + k0 + cb[j] * 8], &Bs[qb[j] * 8]);
    __syncthreads();

    bf16x8_t af[4][2], bfr[2][2];
#pragma unroll
    for (int mt = 0; mt < 4; ++mt) {
      const int r = wm + mt * 16 + l15;
#pragma unroll
      for (int kt = 0; kt < 2; ++kt) {
        const int slot = (kt * 4 + quad) ^ (r & 7);
        af[mt][kt] = *reinterpret_cast<const bf16x8_t*>(&As[r * 64 + slot * 8]);
      }
    }
#pragma unroll
    for (int nt = 0; nt < 2; ++nt) {
      const int r = wn + nt * 16 + l15;
#pragma unroll
      for (int kt = 0; kt < 2; ++kt) {
        const int slot = (kt * 4 + quad) ^ (r & 7);
        bfr[nt][kt] = *reinterpret_cast<const bf16x8_t*>(&Bs[r * 64 + slot * 8]);
      }
    }
#pragma unroll
    for (int mt = 0; mt < 4; ++mt)
#pragma unroll
      for (int nt = 0; nt < 2; ++nt) {
        acc[mt][nt] = __builtin_amdgcn_mfma_f32_16x16x32_bf16(
            af[mt][0], bfr[nt][0], acc[mt][nt], 0, 0, 0);
        acc[mt][nt] = __builtin_amdgcn_mfma_f32_16x16x32_bf16(
            af[mt][1], bfr[nt][1], acc[mt][nt], 0, 0, 0);
      }
  }

#pragma unroll
  for (int mt = 0; mt < 4; ++mt)
#pragma unroll
    for (int i = 0; i < 4; ++i) {
      const size_t rowg = (size_t)(bm + wm + mt * 16 + quad * 4 + i);
#pragma unroll
      for (int nt = 0; nt < 2; ++nt) {
        const int colg = bn + wn + nt * 16 + l15;
        out[rowg * N + colg] = acc[mt][nt][i] + bias[colg];
      }
    }
}

// ---------------------------------------------------------------------------
// MFMA attention: one wave per token, 4 tokens/block, zero LDS (R3-verified).
// ---------------------------------------------------------------------------
__global__ __launch_bounds__(256) void attn_mfma(
    const unsigned short* __restrict__ Qb, const unsigned short* __restrict__ Vb,
    const float* __restrict__ ksum, unsigned short* __restrict__ Ab)
{
  const int t    = blockIdx.x * 4 + (threadIdx.x >> 6);
  const int lane = threadIdx.x & 63;
  const int l15  = lane & 15;
  const int quad = lane >> 4;
  const size_t base = (size_t)t * INNER;

  union VU { bf16x8_t v; unsigned short u[8]; };

  float ksv[2][8];
#pragma unroll
  for (int kt = 0; kt < 2; ++kt) {
    const float4* p = reinterpret_cast<const float4*>(ksum + t * 64 + kt * 32 + quad * 8);
    const float4 a = p[0], b = p[1];
    ksv[kt][0] = a.x; ksv[kt][1] = a.y; ksv[kt][2] = a.z; ksv[kt][3] = a.w;
    ksv[kt][4] = b.x; ksv[kt][5] = b.y; ksv[kt][6] = b.z; ksv[kt][7] = b.w;
  }

  bf16x8_t vs[4][2];
#pragma unroll
  for (int nt = 0; nt < 4; ++nt)
#pragma unroll
    for (int kt = 0; kt < 2; ++kt) {
      VU vr, vo;
      vr.v = *reinterpret_cast<const bf16x8_t*>(
          Vb + base + (size_t)(nt * 16 + l15) * 64 + kt * 32 + quad * 8);
#pragma unroll
      for (int j = 0; j < 8; ++j)
        vo.u[j] = f2bfbits(bfbits2f(vr.u[j]) * ksv[kt][j]);
      vs[nt][kt] = vo.v;
    }

  bf16x8_t qf[4][2];
  float qn[4] = {0.f, 0.f, 0.f, 0.f};
#pragma unroll
  for (int mt = 0; mt < 4; ++mt)
#pragma unroll
    for (int kt = 0; kt < 2; ++kt) {
      VU qr;
      qr.v = *reinterpret_cast<const bf16x8_t*>(
          Qb + base + (size_t)(mt * 16 + l15) * 64 + kt * 32 + quad * 8);
      qf[mt][kt] = qr.v;
#pragma unroll
      for (int j = 0; j < 8; ++j)
        qn[mt] += bfbits2f(qr.u[j]) * ksv[kt][j];
    }
#pragma unroll
  for (int mt = 0; mt < 4; ++mt) {
    qn[mt] += __shfl_xor(qn[mt], 16, 64);
    qn[mt] += __shfl_xor(qn[mt], 32, 64);
  }

  f32x4_t acc[4][4];
#pragma unroll
  for (int mt = 0; mt < 4; ++mt)
#pragma unroll
    for (int nt = 0; nt < 4; ++nt) acc[mt][nt] = (f32x4_t){0.f, 0.f, 0.f, 0.f};

#pragma unroll
  for (int mt = 0; mt < 4; ++mt)
#pragma unroll
    for (int nt = 0; nt < 4; ++nt) {
      acc[mt][nt] = __builtin_amdgcn_mfma_f32_16x16x32_bf16(
          qf[mt][0], vs[nt][0], acc[mt][nt], 0, 0, 0);
      acc[mt][nt] = __builtin_amdgcn_mfma_f32_16x16x32_bf16(
          qf[mt][1], vs[nt][1], acc[mt][nt], 0, 0, 0);
    }

#pragma unroll
  for (int mt = 0; mt < 4; ++mt)
#pragma unroll
    for (int i = 0; i < 4; ++i) {
      const float inv = 1.f / (__shfl(qn[mt], quad * 4 + i, 64) + EPS);
      const size_t roff = base + (size_t)(mt * 16 + quad * 4 + i) * 64;
#pragma unroll
      for (int nt = 0; nt < 4; ++nt)
        Ab[roff + nt * 16 + l15] = f2bfbits(acc[mt][nt][i] * inv);
    }
}

// ---------------------------------------------------------------------------
// Buffers (ws = 130 MB):
//  ws   @0      : Q -> A (in place; K is never materialized)
//  ws   @64MB   : V ; first 8MB reused for Wo^T after attn
//  ws   @128MB  : ks (fp32 8192x64, 2MB) — zeroed by prep, atomics by gemm_kv
//  d_out@0      : Xb (bf16 8192x1024, 16MB)       — dead before gemm_out writes
//  d_out@16MB   : WtKV (bf16 8192x1024, 16MB)     — then WqT (8MB)
// Launches (7): prep, gemm_kv, tcast(Wq), gemmQ, attn, tcast(Wo), gemm_out.
// ---------------------------------------------------------------------------
extern "C" void kernel_launch(void* const* d_in, const int* in_sizes, int n_in,
                              void* d_out, int out_size, void* d_ws, size_t ws_size,
                              hipStream_t stream)
{
  const float* x  = (const float*)d_in[0];
  const float* Wq = (const float*)d_in[1];
  const float* Wk = (const float*)d_in[2];
  const float* Wv = (const float*)d_in[3];
  const float* Wo = (const float*)d_in[4];
  const float* bo = (const float*)d_in[5];
  float* out = (float*)d_out;

  uint8_t* ws = (uint8_t*)d_ws;
  const size_t HALF = (size_t)M_TOK * INNER * sizeof(bf16);  // 64 MB
  unsigned short* QA  = (unsigned short*)ws;            // Q -> A
  unsigned short* Vb  = (unsigned short*)(ws + HALF);   // V ; then Wo^T
  float* ks           = (float*)(ws + 2 * HALF);

  unsigned short* Xb   = (unsigned short*)d_out;                           // 16 MB
  unsigned short* WtKV = (unsigned short*)((uint8_t*)d_out + (16u << 20)); // 16 MB
  unsigned short* WqT  = WtKV;   // reused after gemm_kv
  unsigned short* Wot  = Vb;     // Wo^T over dead V (after attn)

  const dim3 blk(256);

  // cast x, zero ks, transpose Wk & Wv — one launch
  prep_kernel<<<dim3(128, 32, 3), blk, 0, stream>>>(x, Wk, Wv, Xb, WtKV, ks);

  gemm_kv<<<dim3(2 * INNER / 128, M_TOK / 128), blk, 0, stream>>>(
      Xb, WtKV, Vb, ks, DIM);

  tcast_kernel<<<dim3(INNER / 32, DIM / 32), blk, 0, stream>>>(
      Wq, WqT, DIM, INNER);

  gemm_bf16<2><<<dim3(INNER / 128, M_TOK / 128), blk, 0, stream>>>(
      Xb, WqT, QA, M_TOK, INNER, DIM);  // Q

  attn_mfma<<<dim3(M_TOK / 4), blk, 0, stream>>>(QA, Vb, ks, QA);  // A in place

  tcast_kernel<<<dim3(DIM / 32, INNER / 32), blk, 0, stream>>>(
      Wo, Wot, INNER, DIM);  // over dead V

  gemm_out_bf16<<<dim3(DIM / 64, M_TOK / 128), blk, 0, stream>>>(
      QA, Wot, bo, out, M_TOK, DIM, INNER);
}